// Round 1
// baseline (1705.705 us; speedup 1.0000x reference)
//
#include <hip/hip_runtime.h>

#define TPB 256

__device__ __forceinline__ void atomAddF(float* p, float v) {
    __hip_atomic_fetch_add(p, v, __ATOMIC_RELAXED, __HIP_MEMORY_SCOPE_AGENT);
}

// Pass 1: per-row degree counters. Packed: high32 = count of non-self edges,
// low32 = sum of cc[col] over non-self edges. One u64 atomic per edge.
__global__ void k_deg(const int* __restrict__ ei, const int* __restrict__ cc,
                      unsigned long long* __restrict__ deg, int E) {
    int e = blockIdx.x * blockDim.x + threadIdx.x;
    if (e >= E) return;
    int c = ei[e];       // col = edge_index[0]
    int r = ei[E + e];   // row = edge_index[1]
    if (r != c) {
        unsigned long long add = 0x100000000ULL + (unsigned long long)(cc[c] & 1);
        atomicAdd(&deg[r], add);
    }
}

// Pass 2: D^-0.5 for the four normalizations (deg always >= 1, so rsqrt is safe).
__global__ void k_dinv(const unsigned long long* __restrict__ deg,
                       const int* __restrict__ cc,
                       float* __restrict__ dl, float* __restrict__ dh,
                       float* __restrict__ dll, float* __restrict__ dhh, int n) {
    int i = blockIdx.x * blockDim.x + threadIdx.x;
    if (i >= n) return;
    unsigned long long d = deg[i];
    float cnt = (float)(unsigned)(d >> 32);
    float ccs = (float)(unsigned)(d & 0xffffffffu);
    float c = (float)cc[i];
    dl[i]  = rsqrtf(c * cnt + 1.0f);
    dh[i]  = rsqrtf((1.0f - c) * cnt + 1.0f);
    dll[i] = rsqrtf(ccs + 1.0f);
    dhh[i] = rsqrtf(cnt - ccs + 1.0f);
}

// SpMM pass 1: one wave per edge (lane = feature). Each edge goes to exactly
// one of accL (cc[row]==1) / accH (cc[row]==0). Wave-uniform branch.
__global__ void k_spmm1(const int* __restrict__ ei, const int* __restrict__ cc,
                        const float* __restrict__ x,
                        const float* __restrict__ dl, const float* __restrict__ dh,
                        float* __restrict__ accL, float* __restrict__ accH, int E) {
    int total = E << 6;
    int stride = gridDim.x * blockDim.x;
    for (int t = blockIdx.x * blockDim.x + threadIdx.x; t < total; t += stride) {
        int e = t >> 6, f = t & 63;
        int c = ei[e], r = ei[E + e];
        if (r == c) continue;
        float xv = x[(c << 6) + f];
        if (cc[r]) {
            atomAddF(&accL[(r << 6) + f], dl[r] * dl[c] * xv);
        } else {
            atomAddF(&accH[(r << 6) + f], dh[r] * dh[c] * xv);
        }
    }
}

// Dense layer 1: per node, 4 fused GEMVs (64x64) + diag term + ReLU.
// Wave = node, lane = output feature. agg reads are wave-broadcast, W reads coalesced.
__global__ void k_dense1(const float* __restrict__ x,
                         const float* __restrict__ accL, const float* __restrict__ accH,
                         const float* __restrict__ dl, const float* __restrict__ dh,
                         const float* __restrict__ W1l, const float* __restrict__ W1r,
                         const float* __restrict__ W3l, const float* __restrict__ W3r,
                         float* __restrict__ XL, float* __restrict__ XH, int n) {
    int t = blockIdx.x * blockDim.x + threadIdx.x;
    int i = t >> 6, f = t & 63;
    if (i >= n) return;
    float dli = dl[i]; dli *= dli;   // d^2 (diagonal of A_hat)
    float dhi = dh[i]; dhi *= dhi;
    const float* xi = x + (i << 6);
    const float* aL = accL + (i << 6);
    const float* aH = accH + (i << 6);
    float sl = 0.f, sh = 0.f;
    #pragma unroll
    for (int k = 0; k < 64; ++k) {
        float xv = xi[k];
        float al = fmaf(dli, xv, aL[k]);
        float ah = fmaf(dhi, xv, aH[k]);
        sl = fmaf(al, W1l[(k << 6) + f], sl);
        sl = fmaf(xv, W1r[(k << 6) + f], sl);
        sh = fmaf(ah, W3l[(k << 6) + f], sh);
        sh = fmaf(xv, W3r[(k << 6) + f], sh);
    }
    XL[(i << 6) + f] = fmaxf(sl, 0.f);
    XH[(i << 6) + f] = fmaxf(sh, 0.f);
}

// SpMM pass 2: gate on cc[col]; gathers from XL or XH accordingly.
__global__ void k_spmm2(const int* __restrict__ ei, const int* __restrict__ cc,
                        const float* __restrict__ XL, const float* __restrict__ XH,
                        const float* __restrict__ dll, const float* __restrict__ dhh,
                        float* __restrict__ accL, float* __restrict__ accH, int E) {
    int total = E << 6;
    int stride = gridDim.x * blockDim.x;
    for (int t = blockIdx.x * blockDim.x + threadIdx.x; t < total; t += stride) {
        int e = t >> 6, f = t & 63;
        int c = ei[e], r = ei[E + e];
        if (r == c) continue;
        if (cc[c]) {
            atomAddF(&accL[(r << 6) + f], dll[r] * dll[c] * XL[(c << 6) + f]);
        } else {
            atomAddF(&accH[(r << 6) + f], dhh[r] * dhh[c] * XH[(c << 6) + f]);
        }
    }
}

// Final: layer-2 dense (4 GEMVs + diag), xm = x@WX, lambda mix + ReLU,
// then 64->C projection via LDS (wave-local), + bias. One kernel, no xf buffer.
__global__ __launch_bounds__(TPB) void k_final(
        const float* __restrict__ x,
        const float* __restrict__ XL, const float* __restrict__ XH,
        const float* __restrict__ accL, const float* __restrict__ accH,
        const float* __restrict__ dll, const float* __restrict__ dhh,
        const int* __restrict__ cc,
        const float* __restrict__ W2l, const float* __restrict__ W2r,
        const float* __restrict__ W4l, const float* __restrict__ W4r,
        const float* __restrict__ WX,
        const float* __restrict__ lam1, const float* __restrict__ lam2,
        const float* __restrict__ linW, const float* __restrict__ linb,
        float* __restrict__ out, int n, int C) {
    __shared__ float xfs[TPB];
    int t = blockIdx.x * blockDim.x + threadIdx.x;
    int i = t >> 6, f = t & 63;
    float xf = 0.f;
    if (i < n) {
        float e0 = expf(lam1[0]), e1 = expf(lam1[1]);
        float inv1 = 1.f / (e0 + e1);
        float lamxl = e0 * inv1, laml = e1 * inv1;
        float g0 = expf(lam2[0]), g1 = expf(lam2[1]);
        float inv2 = 1.f / (g0 + g1);
        float lamxh = g0 * inv2, lamh = g1 * inv2;
        float c = (float)cc[i];
        float lamx = lamxl * c + lamxh * (1.f - c);
        float dlli = dll[i]; dlli *= dlli;
        float dhhi = dhh[i]; dhhi *= dhhi;
        const float* xi = x + (i << 6);
        const float* xl = XL + (i << 6);
        const float* xh = XH + (i << 6);
        const float* aL = accL + (i << 6);
        const float* aH = accH + (i << 6);
        float sl = 0.f, sh = 0.f, sm = 0.f;
        #pragma unroll
        for (int k = 0; k < 64; ++k) {
            float xlv = xl[k], xhv = xh[k], xv = xi[k];
            float al = fmaf(dlli, xlv, aL[k]);
            float ah = fmaf(dhhi, xhv, aH[k]);
            sl = fmaf(al,  W2l[(k << 6) + f], sl);
            sl = fmaf(xlv, W2r[(k << 6) + f], sl);
            sh = fmaf(ah,  W4l[(k << 6) + f], sh);
            sh = fmaf(xhv, W4r[(k << 6) + f], sh);
            sm = fmaf(xv,  WX[(k << 6) + f], sm);
        }
        xf = fmaxf(lamx * sm + laml * sl + lamh * sh, 0.f);
    }
    xfs[threadIdx.x] = xf;
    __syncthreads();
    if (i < n && f < C) {
        const float* xrow = &xfs[threadIdx.x & ~63];  // this wave's 64 xf values
        float s = linb[f];
        #pragma unroll
        for (int k = 0; k < 64; ++k)
            s = fmaf(xrow[k], linW[k * C + f], s);
        out[i * C + f] = s;
    }
}

extern "C" void kernel_launch(void* const* d_in, const int* in_sizes, int n_in,
                              void* d_out, int out_size, void* d_ws, size_t ws_size,
                              hipStream_t stream) {
    const float* x    = (const float*)d_in[0];
    const int*   ei   = (const int*)d_in[1];
    const int*   cc   = (const int*)d_in[2];
    const float* W1l  = (const float*)d_in[3];
    const float* W1r  = (const float*)d_in[4];
    const float* W2l  = (const float*)d_in[5];
    const float* W2r  = (const float*)d_in[6];
    const float* W3l  = (const float*)d_in[7];
    const float* W3r  = (const float*)d_in[8];
    const float* W4l  = (const float*)d_in[9];
    const float* W4r  = (const float*)d_in[10];
    const float* WX   = (const float*)d_in[11];
    const float* lam1 = (const float*)d_in[12];
    const float* lam2 = (const float*)d_in[13];
    const float* linW = (const float*)d_in[14];
    const float* linb = (const float*)d_in[15];

    int n = in_sizes[2];
    int E = in_sizes[1] / 2;
    int C = in_sizes[15];

    char* ws = (char*)d_ws;
    size_t nf = (size_t)n * 64 * sizeof(float);
    float* accA = (float*)ws; ws += nf;     // contiguous with accB for one memset
    float* accB = (float*)ws; ws += nf;
    float* XL   = (float*)ws; ws += nf;
    float* XH   = (float*)ws; ws += nf;
    float* dl   = (float*)ws; ws += (size_t)n * sizeof(float);
    float* dh   = (float*)ws; ws += (size_t)n * sizeof(float);
    float* dll  = (float*)ws; ws += (size_t)n * sizeof(float);
    float* dhh  = (float*)ws; ws += (size_t)n * sizeof(float);
    unsigned long long* deg = (unsigned long long*)ws; ws += (size_t)n * sizeof(unsigned long long);

    hipMemsetAsync(deg, 0, (size_t)n * sizeof(unsigned long long), stream);
    hipMemsetAsync(accA, 0, 2 * nf, stream);

    k_deg<<<(E + TPB - 1) / TPB, TPB, 0, stream>>>(ei, cc, deg, E);
    k_dinv<<<(n + TPB - 1) / TPB, TPB, 0, stream>>>(deg, cc, dl, dh, dll, dhh, n);

    const int spmmBlocks = 8192;
    k_spmm1<<<spmmBlocks, TPB, 0, stream>>>(ei, cc, x, dl, dh, accA, accB, E);
    k_dense1<<<((size_t)n * 64 + TPB - 1) / TPB, TPB, 0, stream>>>(
        x, accA, accB, dl, dh, W1l, W1r, W3l, W3r, XL, XH, n);

    hipMemsetAsync(accA, 0, 2 * nf, stream);
    k_spmm2<<<spmmBlocks, TPB, 0, stream>>>(ei, cc, XL, XH, dll, dhh, accA, accB, E);
    k_final<<<((size_t)n * 64 + TPB - 1) / TPB, TPB, 0, stream>>>(
        x, XL, XH, accA, accB, dll, dhh, cc,
        W2l, W2r, W4l, W4r, WX, lam1, lam2, linW, linb,
        (float*)d_out, n, C);
}